// Round 5
// baseline (155.947 us; speedup 1.0000x reference)
//
#include <hip/hip_runtime.h>
#include <math.h>

#define G_GAMES 8
#define D_IN 512
#define H1 1024
#define H2 1024
#define A_DIM 128
#define B_ROWS 8192

typedef short bf16x8 __attribute__((ext_vector_type(8)));
typedef float f32x4 __attribute__((ext_vector_type(4)));

// ---------- workspace layout (bytes) ----------
#define WS_OFF   0u
#define WS_PERM  256u
#define WS_SPERM 33280u                               // B*D_IN bf16
#define WS_W1T   (WS_SPERM + B_ROWS*D_IN*2u)          // G*H1*D_IN bf16
#define WS_W2T   (WS_W1T + G_GAMES*D_IN*H1*2u)        // H2*H1 bf16
#define WS_W3T   (WS_W2T + (unsigned)H1*H2*2u)        // G*A*H2 bf16
#define WS_H1    (WS_W3T + G_GAMES*H2*A_DIM*2u)       // B*H1 bf16
#define WS_HF    WS_SPERM                             // aliases sPerm (dead after gemm1)

__device__ __forceinline__ unsigned short f2bf(float x) {
  union { float f; unsigned int u; } v; v.f = x;
  unsigned int r = v.u + 0x7fffu + ((v.u >> 16) & 1u);
  return (unsigned short)(r >> 16);
}

__device__ __forceinline__ void async_load16(const void* gptr, void* ldsptr) {
  __builtin_amdgcn_global_load_lds(
      (const __attribute__((address_space(1))) unsigned int*)gptr,
      (__attribute__((address_space(3))) unsigned int*)ldsptr,
      16, 0, 0);
}

// ---------------- stable counting sort (256 threads, 32 elems each) ----------------
__device__ void sort_256(const int* __restrict__ idx, int* __restrict__ perm,
                         int* __restrict__ off) {
  __shared__ int wtot[4][9];
  __shared__ int wbase[4][9];
  __shared__ int offs[9];
  const int t = threadIdx.x, lane = t & 63, wave = t >> 6;
  int my[32];
#pragma unroll
  for (int i = 0; i < 8; ++i) {
    const int4 a = *(const int4*)(idx + t * 32 + i * 4);
    my[i*4+0] = a.x; my[i*4+1] = a.y; my[i*4+2] = a.z; my[i*4+3] = a.w;
  }
  int local[8] = {0,0,0,0,0,0,0,0};
#pragma unroll
  for (int i = 0; i < 32; ++i) local[my[i]]++;
  int incl[8];
#pragma unroll
  for (int g = 0; g < 8; ++g) {
    int v = local[g];
#pragma unroll
    for (int d = 1; d < 64; d <<= 1) {
      const int n = __shfl_up(v, d);
      if (lane >= d) v += n;
    }
    incl[g] = v;
  }
  if (lane == 63) {
#pragma unroll
    for (int g = 0; g < 8; ++g) wtot[wave][g] = incl[g];
  }
  __syncthreads();
  if (t < 8) {
    int s = 0;
#pragma unroll
    for (int w = 0; w < 4; ++w) { wbase[w][t] = s; s += wtot[w][t]; }
    wtot[0][t] = s;
  }
  __syncthreads();
  if (t == 0) {
    int s = 0;
#pragma unroll
    for (int g = 0; g < 8; ++g) { offs[g] = s; off[g] = s; s += wtot[0][g]; }
    offs[8] = s; off[8] = s;
  }
  __syncthreads();
  int start[8];
#pragma unroll
  for (int g = 0; g < 8; ++g)
    start[g] = offs[g] + wbase[wave][g] + (incl[g] - local[g]);
#pragma unroll
  for (int i = 0; i < 32; ++i) {
    const int g = my[i];
    perm[start[g]++] = t * 32 + i;
  }
}

// ------------- fp32 [R][C] -> bf16 [C][R] transpose tile (64x64) -------------
__device__ void trans_tile(const float* __restrict__ in,
                           unsigned short* __restrict__ out,
                           int R, int C, int xt, int yt, int z) {
  in  += (size_t)z * R * C;
  out += (size_t)z * R * C;
  __shared__ float tile[64][65];
  const int c0 = xt * 64, r0 = yt * 64;
  const int tx = threadIdx.x & 63, ty = threadIdx.x >> 6;
#pragma unroll
  for (int rr = ty; rr < 64; rr += 4)
    tile[rr][tx] = in[(size_t)(r0 + rr) * C + c0 + tx];
  __syncthreads();
#pragma unroll
  for (int cc = ty; cc < 64; cc += 4)
    out[(size_t)(c0 + cc) * R + r0 + tx] = f2bf(tile[tx][cc]);
}

// blocks: [0,1024) W1, [1024,1280) W2, [1280,1536) W3, 1536 = sort
__global__ __launch_bounds__(256) void k_pre1(const float* __restrict__ W1,
                                              const float* __restrict__ W2,
                                              const float* __restrict__ W3,
                                              const int* __restrict__ idx,
                                              unsigned short* __restrict__ W1T,
                                              unsigned short* __restrict__ W2T,
                                              unsigned short* __restrict__ W3T,
                                              int* __restrict__ perm,
                                              int* __restrict__ off) {
  const int b = blockIdx.x;
  if (b < 1024) {
    const int z = b >> 7, r = b & 127;
    trans_tile(W1, W1T, D_IN, H1, r & 15, r >> 4, z);
  } else if (b < 1280) {
    const int r = b - 1024;
    trans_tile(W2, W2T, H1, H2, r & 15, r >> 4, 0);
  } else if (b < 1536) {
    const int r = (b - 1280) & 31, z = (b - 1280) >> 5;
    trans_tile(W3, W3T, H2, A_DIM, r & 1, r >> 1, z);
  } else {
    sort_256(idx, perm, off);
  }
}

// ------------- gather state rows by perm, fp32 -> bf16 -------------
__global__ __launch_bounds__(256) void k_gather(const float* __restrict__ state,
                                                const int* __restrict__ perm,
                                                unsigned short* __restrict__ sPerm) {
  const int p = blockIdx.x * 2 + (threadIdx.x >> 7);
  const int c = (threadIdx.x & 127) << 2;
  const int src = perm[p];
  const float4 v = *(const float4*)(state + (size_t)src * D_IN + c);
  ushort4 o;
  o.x = f2bf(v.x); o.y = f2bf(v.y); o.z = f2bf(v.z); o.w = f2bf(v.w);
  *(ushort4*)(sPerm + (size_t)p * D_IN + c) = o;
}

// ------------- 512-thread dbuf MFMA core: 128x128 tile, BK=64, 8 waves 2x4, 4x2 accs ----
// Wave w (w=0..7): wm=w&1 (M half), wn=w>>1 (N quarter) -> wave owns 64x32.
// acc = 4x2 of 16x16 => 32 AGPR/wave; target <=128 unified regs -> 4 waves/SIMD,
// 16 waves/CU (2 blocks/CU). LDS row = 64 elems = 128B = 8 units; unit ^= (row&7).
// Single barrier per iter: sync (drains tile-k loads issued last iter -> cheap),
// issue tile k+1, compute tile k.  smem: A0@0 A1@16K B0@32K B1@48K (64 KB).
template <int KTOT>
__device__ __forceinline__ void gemm_db8(const unsigned short* const* aP,
                                         const unsigned short* const* bP,
                                         char* smem, int tid, f32x4 acc[4][2]) {
  const int lane = tid & 63, wave = tid >> 6;
  const int wm = wave & 1, wn = wave >> 1;
  const int sw = lane & 15, quad = lane >> 4;
  const int mA = wm * 64 + sw;
  const int nB = wn * 32 + sw;
  char* A0 = smem;          char* A1 = smem + 16384;
  char* B0 = smem + 32768;  char* B1 = smem + 49152;
  const int NIT = KTOT >> 6;
#pragma unroll
  for (int c = 0; c < 2; ++c) {
    async_load16(aP[c], A0 + (wave * 16 + c * 8) * 128);
    async_load16(bP[c], B0 + (wave * 16 + c * 8) * 128);
  }
#pragma unroll 2
  for (int k = 0; k < NIT; ++k) {
    __syncthreads();
    char* A = (k & 1) ? A1 : A0;
    char* B = (k & 1) ? B1 : B0;
    if (k + 1 < NIT) {
      char* An = (k & 1) ? A0 : A1;
      char* Bn = (k & 1) ? B0 : B1;
      const int koff = (k + 1) << 6;
#pragma unroll
      for (int c = 0; c < 2; ++c) {
        async_load16(aP[c] + koff, An + (wave * 16 + c * 8) * 128);
        async_load16(bP[c] + koff, Bn + (wave * 16 + c * 8) * 128);
      }
    }
#pragma unroll
    for (int ks = 0; ks < 2; ++ks) {
      const int u = ((((ks << 2) + quad) ^ (sw & 7)) << 4);
      bf16x8 aF[4], bF[2];
#pragma unroll
      for (int i = 0; i < 4; ++i)
        aF[i] = *(const bf16x8*)(A + (mA + i * 16) * 128 + u);
#pragma unroll
      for (int j = 0; j < 2; ++j)
        bF[j] = *(const bf16x8*)(B + (nB + j * 16) * 128 + u);
#pragma unroll
      for (int i = 0; i < 4; ++i)
#pragma unroll
        for (int j = 0; j < 2; ++j)
          acc[i][j] = __builtin_amdgcn_mfma_f32_16x16x32_bf16(aF[i], bF[j], acc[i][j], 0, 0, 0);
    }
  }
}

__device__ __forceinline__ bool seg_map(const int* __restrict__ off, int T,
                                        int& g, int& seg1, int& row0) {
  int base = 0;
  for (int gg = 0; gg < 8; ++gg) {
    const int s = off[gg], e = off[gg + 1];
    const int nt = (e - s + 127) >> 7;
    if (T < base + nt) { g = gg; seg1 = e; row0 = s + (T - base) * 128; return true; }
    base += nt;
  }
  return false;
}

__device__ __forceinline__ bool seg_map32(const int* __restrict__ off, int T,
                                          int& g, int& seg1, int& row0) {
  int base = 0;
  for (int gg = 0; gg < 8; ++gg) {
    const int s = off[gg], e = off[gg + 1];
    const int nt = (e - s + 31) >> 5;
    if (T < base + nt) { g = gg; seg1 = e; row0 = s + (T - base) * 32; return true; }
    base += nt;
  }
  return false;
}

// Epilogue (512 thr): stage bf16 C-tile in LDS (stride 264 B), copy out as full
// 256-B row segments (16 B/lane) — no partial-line RMW. Needs 33792 B of smem.
__device__ __forceinline__ void epi_bf16_512(char* smem, const f32x4 acc[4][2],
                                             const float* bj, int tid,
                                             unsigned short* __restrict__ outp,
                                             size_t ldOut, int row0, int col0,
                                             int vrows) {
  const int lane = tid & 63, wave = tid >> 6;
  const int wm = wave & 1, wn = wave >> 1;
  const int sw = lane & 15, quad = lane >> 4;
  __syncthreads();  // all LDS reads of K-loop done before overwrite
#pragma unroll
  for (int i = 0; i < 4; ++i)
#pragma unroll
    for (int j = 0; j < 2; ++j)
#pragma unroll
      for (int r = 0; r < 4; ++r) {
        const int row = wm * 64 + i * 16 + quad * 4 + r;
        const int col = wn * 32 + j * 16 + sw;
        const float v = fmaxf(acc[i][j][r] + bj[j], 0.0f);
        *(unsigned short*)(smem + row * 264 + col * 2) = f2bf(v);
      }
  __syncthreads();
#pragma unroll
  for (int q = 0; q < 4; ++q) {
    const int idxq = q * 512 + tid;   // 2048 chunks: 128 rows x 16 chunks of 16B
    const int row = idxq >> 4, ch = idxq & 15;
    if (row < vrows) {
      const uint2 lo = *(const uint2*)(smem + row * 264 + ch * 16);
      const uint2 hi = *(const uint2*)(smem + row * 264 + ch * 16 + 8);
      uint4 v; v.x = lo.x; v.y = lo.y; v.z = hi.x; v.w = hi.y;
      *(uint4*)((char*)outp + ((size_t)(row0 + row) * ldOut + col0 + ch * 8) * 2) = v;
    }
  }
}

// ------------- GEMM1: h1[p] = relu(sPerm[p] @ W1[g] + b1[g]), grouped -------------
__global__ __launch_bounds__(512, 4) void k_gemm1(const unsigned short* __restrict__ sPerm,
                                                  const unsigned short* __restrict__ W1T,
                                                  const float* __restrict__ b1,
                                                  const int* __restrict__ off,
                                                  unsigned short* __restrict__ h1out) {
  __shared__ char smem[65536];
  int g, seg1, row0;
  if (!seg_map(off, blockIdx.x, g, seg1, row0)) return;
  const int col0 = blockIdx.y * 128;
  const int tid = threadIdx.x, lane = tid & 63, wave = tid >> 6;
  const int gcol = ((lane & 7) ^ (lane >> 3)) << 3;
  const unsigned short* aP[2];
  const unsigned short* bP[2];
#pragma unroll
  for (int c = 0; c < 2; ++c) {
    const int rl = wave * 16 + c * 8 + (lane >> 3);
    int p = row0 + rl;
    if (p > seg1 - 1) p = seg1 - 1;
    aP[c] = sPerm + (size_t)p * D_IN + gcol;
    bP[c] = W1T + (size_t)g * H1 * D_IN + (size_t)(col0 + rl) * D_IN + gcol;
  }
  f32x4 acc[4][2] = {};
  gemm_db8<D_IN>(aP, bP, smem, tid, acc);
  const int wn = wave >> 1, sw = lane & 15;
  const float* bg = b1 + g * H1;
  float bj[2];
#pragma unroll
  for (int j = 0; j < 2; ++j) bj[j] = bg[col0 + wn * 32 + j * 16 + sw];
  const int vrows = min(128, seg1 - row0);
  epi_bf16_512(smem, acc, bj, tid, h1out, H1, row0, col0, vrows);
}

// ------------- GEMM2: h_f = relu(h1 @ W2 + b2) -------------
__global__ __launch_bounds__(512, 4) void k_gemm2(const unsigned short* __restrict__ h1in,
                                                  const unsigned short* __restrict__ W2T,
                                                  const float* __restrict__ b2,
                                                  unsigned short* __restrict__ hfout) {
  __shared__ char smem[65536];
  const int row0 = blockIdx.x * 128, col0 = blockIdx.y * 128;
  const int tid = threadIdx.x, lane = tid & 63, wave = tid >> 6;
  const int gcol = ((lane & 7) ^ (lane >> 3)) << 3;
  const unsigned short* aP[2];
  const unsigned short* bP[2];
#pragma unroll
  for (int c = 0; c < 2; ++c) {
    const int rl = wave * 16 + c * 8 + (lane >> 3);
    aP[c] = h1in + (size_t)(row0 + rl) * H1 + gcol;
    bP[c] = W2T + (size_t)(col0 + rl) * H1 + gcol;
  }
  f32x4 acc[4][2] = {};
  gemm_db8<H1>(aP, bP, smem, tid, acc);
  const int wn = wave >> 1, sw = lane & 15;
  float bj[2];
#pragma unroll
  for (int j = 0; j < 2; ++j) bj[j] = b2[col0 + wn * 32 + j * 16 + sw];
  epi_bf16_512(smem, acc, bj, tid, hfout, H2, row0, col0, 128);
}

// ------------- GEMM3: 32x128 tiles, dbuf BK=64; out[perm[q]] = tanh(...) -------------
// smem: A0@0(4K) A1@4K B0@8K(16K) B1@24K ; C-stage overlays @0 (32 x 528 B = 16.5 KB)
__global__ __launch_bounds__(256) void k_gemm3(const unsigned short* __restrict__ hf,
                                               const unsigned short* __restrict__ W3T,
                                               const float* __restrict__ b3,
                                               const int* __restrict__ off,
                                               const int* __restrict__ perm,
                                               float* __restrict__ outp) {
  __shared__ char smem[40960];
  int g, seg1, row0;
  if (!seg_map32(off, blockIdx.x, g, seg1, row0)) return;
  const int tid = threadIdx.x, lane = tid & 63, wave = tid >> 6;
  const int wm = wave & 1, wn = wave >> 1;
  const int sw = lane & 15, quad = lane >> 4;
  const int gcol = ((lane & 7) ^ (lane >> 3)) << 3;
  int q0 = row0 + wave * 8 + (lane >> 3);
  if (q0 > seg1 - 1) q0 = seg1 - 1;
  const unsigned short* aP = hf + (size_t)perm[q0] * H2 + gcol;
  const unsigned short* bP[4];
#pragma unroll
  for (int c = 0; c < 4; ++c) {
    const int rl = wave * 32 + c * 8 + (lane >> 3);
    bP[c] = W3T + (size_t)g * A_DIM * H2 + (size_t)rl * H2 + gcol;
  }
  char* A0 = smem;         char* A1 = smem + 4096;
  char* B0 = smem + 8192;  char* B1 = smem + 24576;
  const int mA = wm * 16 + sw;
  const int nB = wn * 64 + sw;
  f32x4 acc[4] = {};
  async_load16(aP, A0 + (wave * 8) * 128);
#pragma unroll
  for (int c = 0; c < 4; ++c)
    async_load16(bP[c], B0 + (wave * 32 + c * 8) * 128);
#pragma unroll 2
  for (int k = 0; k < (H2 >> 6); ++k) {
    __syncthreads();
    char* A = (k & 1) ? A1 : A0;
    char* B = (k & 1) ? B1 : B0;
    if (k + 1 < (H2 >> 6)) {
      char* An = (k & 1) ? A0 : A1;
      char* Bn = (k & 1) ? B0 : B1;
      const int koff = (k + 1) << 6;
      async_load16(aP + koff, An + (wave * 8) * 128);
#pragma unroll
      for (int c = 0; c < 4; ++c)
        async_load16(bP[c] + koff, Bn + (wave * 32 + c * 8) * 128);
    }
#pragma unroll
    for (int ks = 0; ks < 2; ++ks) {
      const int u = ((((ks << 2) + quad) ^ (sw & 7)) << 4);
      const bf16x8 aF = *(const bf16x8*)(A + mA * 128 + u);
      bf16x8 bF[4];
#pragma unroll
      for (int j = 0; j < 4; ++j)
        bF[j] = *(const bf16x8*)(B + (nB + j * 16) * 128 + u);
#pragma unroll
      for (int j = 0; j < 4; ++j)
        acc[j] = __builtin_amdgcn_mfma_f32_16x16x32_bf16(aF, bF[j], acc[j], 0, 0, 0);
    }
  }
  const float* bg = b3 + g * A_DIM;
  float bj[4];
#pragma unroll
  for (int j = 0; j < 4; ++j) bj[j] = bg[wn * 64 + j * 16 + sw];
  __syncthreads();
#pragma unroll
  for (int j = 0; j < 4; ++j)
#pragma unroll
    for (int r = 0; r < 4; ++r) {
      const int row = wm * 16 + quad * 4 + r;
      const int col = wn * 64 + j * 16 + sw;
      *(float*)(smem + row * 528 + col * 4) = tanhf(acc[j][r] + bj[j]);
    }
  __syncthreads();
#pragma unroll
  for (int qq = 0; qq < 4; ++qq) {
    const int idxq = qq * 256 + tid;  // 1024 chunks: 32 rows x 32 chunks of 16B
    const int row = idxq >> 5, ch = idxq & 31;
    if (row0 + row < seg1) {
      const uint4 v = *(const uint4*)(smem + row * 528 + ch * 16);
      *(uint4*)((char*)outp + ((size_t)perm[row0 + row] * A_DIM + ch * 4) * 4) = v;
    }
  }
}

extern "C" void kernel_launch(void* const* d_in, const int* in_sizes, int n_in,
                              void* d_out, int out_size, void* d_ws, size_t ws_size,
                              hipStream_t stream) {
  (void)in_sizes; (void)n_in; (void)out_size; (void)ws_size;
  const float* state = (const float*)d_in[0];
  const int*   idx   = (const int*)d_in[1];
  const float* W1    = (const float*)d_in[2];
  const float* b1    = (const float*)d_in[3];
  const float* W2    = (const float*)d_in[4];
  const float* b2    = (const float*)d_in[5];
  const float* W3    = (const float*)d_in[6];
  const float* b3    = (const float*)d_in[7];
  float* outp = (float*)d_out;
  char* ws = (char*)d_ws;
  int* off  = (int*)(ws + WS_OFF);
  int* perm = (int*)(ws + WS_PERM);
  unsigned short* sPerm = (unsigned short*)(ws + WS_SPERM);
  unsigned short* W1T   = (unsigned short*)(ws + WS_W1T);
  unsigned short* W2T   = (unsigned short*)(ws + WS_W2T);
  unsigned short* W3T   = (unsigned short*)(ws + WS_W3T);
  unsigned short* h1    = (unsigned short*)(ws + WS_H1);
  unsigned short* hf    = (unsigned short*)(ws + WS_HF);

  hipLaunchKernelGGL(k_pre1, dim3(1537), dim3(256), 0, stream,
                     W1, W2, W3, idx, W1T, W2T, W3T, perm, off);
  hipLaunchKernelGGL(k_gather, dim3(B_ROWS / 2), dim3(256), 0, stream, state, perm, sPerm);
  hipLaunchKernelGGL(k_gemm1, dim3(72, 8), dim3(512), 0, stream, sPerm, W1T, b1, off, h1);
  hipLaunchKernelGGL(k_gemm2, dim3(64, 8), dim3(512), 0, stream, h1, W2T, b2, hf);
  hipLaunchKernelGGL(k_gemm3, dim3(264), dim3(256), 0, stream, hf, W3T, b3, off, perm, outp);
}